// Round 5
// baseline (66.376 us; speedup 1.0000x reference)
//
#include <hip/hip_runtime.h>

#define H 1024
#define W 1024
#define NPIX (H * W)
#define WW 16          // 64-row words per column
#define INF_F 1e12f
#define THREADS 256
#define CB 512         // main columns per row-half block
#define RBLOCKS (2 * H)
#define BIG (1 << 29)

// ---------------------------------------------------------------------------
// Exact vertical nearest-site distance for pixel (r,c), polarity pol
// (pol=1: sites are 1-pixels; pol=0: sites are 0-pixels). Cold path.
// ---------------------------------------------------------------------------
__device__ __noinline__ int vert_dist_full(const unsigned long long* __restrict__ pw,
                                           int r, int c, int pol) {
  int w = r >> 6, b = r & 63;
  unsigned long long v = pw[w * W + c];
  unsigned long long m_c = pol ? v : ~v;
  int dup = 1 << 30, ddn = 1 << 30;
  unsigned long long am = m_c & ((1ULL << b) - 1ULL);
  if (am) {
    dup = b - (63 - __builtin_clzll(am));
  } else {
    for (int ww = w - 1; ww >= 0; --ww) {
      unsigned long long mv = pw[ww * W + c];
      mv = pol ? mv : ~mv;
      if (mv) { dup = r - (ww * 64 + 63 - __builtin_clzll(mv)); break; }
    }
  }
  unsigned long long bm = m_c >> b;  // includes self
  if (bm) {
    ddn = __builtin_ctzll(bm);
  } else {
    for (int ww = w + 1; ww < WW; ++ww) {
      unsigned long long mv = pw[ww * W + c];
      mv = pol ? mv : ~mv;
      if (mv) { ddn = (ww * 64 + __builtin_ctzll(mv)) - r; break; }
    }
  }
  return min(dup, ddn);
}

// Cold exact continuation/restart of the parabola min. Never taken at p=0.5.
__device__ __noinline__ int horiz_exact(const unsigned long long* __restrict__ pw,
                                        int r, int c, int pol, int best, int dk0) {
  for (int dk = dk0; dk < W; ++dk) {
    int dk2 = dk * dk;
    if (dk2 >= best) break;
    if (c - dk >= 0) {
      int d = vert_dist_full(pw, r, c - dk, pol);
      if (d < H) best = min(best, d * d + dk2);
    }
    if (c + dk < W) {
      int d = vert_dist_full(pw, r, c + dk, pol);
      if (d < H) best = min(best, d * d + dk2);
    }
  }
  return best;
}

// ---------------------------------------------------------------------------
// Kernel A: pack target (0/1 int32) into a bit matrix, column-major bits:
// pw[w*W + c] bit b = (target[(w*64+b)*W + c] != 0). u16 granularity
// (65536 threads, 16 coalesced row-loads each). Unchanged from R4.
// ---------------------------------------------------------------------------
__global__ __launch_bounds__(THREADS) void pack_bits(
    const int* __restrict__ target, unsigned short* __restrict__ pw16) {
  int tg = blockIdx.x * THREADS + threadIdx.x;  // [0, 65536)
  int c = tg & (W - 1);
  int rest = tg >> 10;        // [0, 64)
  int w = rest >> 2;
  int quarter = rest & 3;
  int rbase = w * 64 + quarter * 16;
  unsigned int val = 0;
#pragma unroll
  for (int b = 0; b < 16; ++b) {
    if (target[(rbase + b) * W + c] != 0) val |= (1u << b);
  }
  pw16[((w * W + c) << 2) + quarter] = (unsigned short)val;
}

// ---------------------------------------------------------------------------
// Kernel B: fused vertical EDT + horizontal envelope + product + block
// reduction. HALF a row per block: 2048 blocks x 256 thr = 8 blocks/CU =
// 32 waves/CU (full occupancy; R4 ran at 16), and 2 cols/thread instead of
// 4 halves the serial envelope chain. Exactness: the 32-col halo on each
// side holds REAL vertical distances (computed by threads 0..63, one halo
// col each); out-of-image halo slots get the 255 sentinel, reproducing the
// old border-pad semantics. Cold fallbacks unchanged (operate on the full
// row via pw).
// ---------------------------------------------------------------------------
__global__ __launch_bounds__(THREADS, 8) void fused_edt_row(
    const unsigned long long* __restrict__ pw,
    const float* __restrict__ input,
    double* __restrict__ partials) {
  // byte distances, [pol][32 + (c-cb)]; slots 0..31 and 544..575 are halo
  __shared__ unsigned char sd8[2][CB + 64];
  __shared__ double smem[THREADS / 64];
  const int tid = threadIdx.x;
  const int bid = blockIdx.x;
  const int r = bid >> 1;
  const int cb = (bid & 1) << 9;     // 0 or 512
  const int w = r >> 6, b = r & 63;  // wave-uniform
  const int c0 = cb + (tid << 1);    // 2 consecutive columns per thread

  // hoist the input load: HBM latency overlaps phase 1's VALU
  const float2 iv = *(const float2*)(input + r * W + c0);

  const bool hp = (w > 0), hn = (w < WW - 1);

  // ---- phase 1 loads: 2 main cols (vectorized) + 1 halo col (tid<64) ----
  unsigned long long curv[2], prevv[2], nextv[2];
  *(ulonglong2*)curv = *(const ulonglong2*)(pw + w * W + c0);
  if (hp) *(ulonglong2*)prevv = *(const ulonglong2*)(pw + (w - 1) * W + c0);
  else prevv[0] = prevv[1] = 0ULL;
  if (hn) *(ulonglong2*)nextv = *(const ulonglong2*)(pw + (w + 1) * W + c0);
  else nextv[0] = nextv[1] = 0ULL;

  const int hcol = (tid < 32) ? (cb - 32 + tid) : (cb + CB + (tid - 32));
  const bool hvalid = (tid < 64) && (hcol >= 0) && (hcol < W);
  unsigned long long hcur = 0ULL, hprev = 0ULL, hnext = 0ULL;
  if (hvalid) {
    hcur = pw[w * W + hcol];
    if (hp) hprev = pw[(w - 1) * W + hcol];
    if (hn) hnext = pw[(w + 1) * W + hcol];
  }

  // byte vertical distance from a 3-word window; exact-or-cold-resolved
  auto vdist = [&](unsigned long long cv, unsigned long long pv,
                   unsigned long long nv, int pol, int c) -> unsigned char {
    unsigned long long m_c = pol ? cv : ~cv;
    unsigned long long m_p = hp ? (pol ? pv : ~pv) : 0ULL;
    unsigned long long m_n = hn ? (pol ? nv : ~nv) : 0ULL;
    int d = 1 << 30;
    unsigned long long am = m_c & ((1ULL << b) - 1ULL);
    if (am) d = b - (63 - __builtin_clzll(am));
    else if (m_p) d = b + 1 + __builtin_clzll(m_p);
    unsigned long long bm = m_c >> b;  // includes self
    int dd = 1 << 30;
    if (bm) dd = __builtin_ctzll(bm);
    else if (m_n) dd = (64 - b) + __builtin_ctzll(m_n);
    d = min(d, dd);
    // window-blind (both directions) must be re-resolved exactly
    if (d > 64) d = vert_dist_full(pw, r, c, pol);  // cold (~2^-64)
    return (unsigned char)min(d, 255);
  };

  unsigned char dloc[2][2];  // [pol][k] for the 2 main cols
#pragma unroll
  for (int pol = 0; pol < 2; ++pol) {
#pragma unroll
    for (int k = 0; k < 2; ++k)
      dloc[pol][k] = vdist(curv[k], prevv[k], nextv[k], pol, c0 + k);
    // main store: 2 bytes as one u16; contiguous across threads
    *(unsigned short*)&sd8[pol][32 + (tid << 1)] =
        (unsigned short)((unsigned int)dloc[pol][0] |
                         ((unsigned int)dloc[pol][1] << 8));
  }
  if (tid < 64) {
    int idx = (tid < 32) ? tid : (CB + tid);  // 0..31 | 544..575
#pragma unroll
    for (int pol = 0; pol < 2; ++pol)
      sd8[pol][idx] = hvalid ? vdist(hcur, hprev, hnext, pol, hcol)
                             : (unsigned char)255;
  }
  __syncthreads();

  // ---- phase 2: horizontal envelope + product (2 cols) ----
  double val = 0.0;
  const float ivk[2] = {iv.x, iv.y};
#pragma unroll
  for (int k = 0; k < 2; ++k) {
    const bool t = (dloc[1][k] == 0);  // nearest-one dist 0 <=> t=1
    const int pol = t ? 0 : 1;         // t uses g_t (nearest zero)
    const int own = dloc[pol][k];
    int best = (own == 255) ? BIG : own * own;
    const unsigned char* __restrict__ sg = &sd8[pol][32 + (tid << 1) + k];
    // dk=1,2 unconditionally (branchless; extra probes preserve exactness)
#pragma unroll
    for (int dk = 1; dk <= 2; ++dk) {
      int dl = sg[-dk], dr = sg[dk];
      int gl = (dl == 255) ? BIG : dl * dl;
      int gr = (dr == 255) ? BIG : dr * dr;
      best = min(best, min(gl, gr) + dk * dk);
    }
    for (int dk = 3; dk <= 32; ++dk) {
      int dk2 = dk * dk;
      if (dk2 >= best) break;
      int dl = sg[-dk], dr = sg[dk];
      int gl = (dl == 255) ? BIG : dl * dl;
      int gr = (dr == 255) ? BIG : dr * dr;
      best = min(best, min(gl, gr) + dk2);
    }
    if (best > 1089) {  // cold exact fallback (beyond halo / sentinel)
      int c = c0 + k;
      if (best > 65025) {  // 255-sentinel could have hidden a true min
        int ov = vert_dist_full(pw, r, c, pol);
        best = (ov < H) ? ov * ov : (1 << 30);
        best = horiz_exact(pw, r, c, pol, best, 1);
      } else {
        best = horiz_exact(pw, r, c, pol, best, 33);
      }
    }
    float bestf = (best >= BIG) ? INF_F : (float)best;
    float dist = sqrtf(bestf);
    float sd = t ? (1.0f - dist) : dist;
    val += (double)(ivk[k] * sd);
  }

  // ---- phase 3: block reduction ----
  for (int off = 32; off > 0; off >>= 1)
    val += __shfl_down(val, off, 64);
  int lane = tid & 63, wid = tid >> 6;
  if (lane == 0) smem[wid] = val;
  __syncthreads();
  if (tid == 0)
    partials[bid] = smem[0] + smem[1] + smem[2] + smem[3];
}

// ---------------------------------------------------------------------------
// Kernel C: reduce 2048 partials -> mean scalar.
// ---------------------------------------------------------------------------
__global__ __launch_bounds__(THREADS) void reduce_partials(
    const double* __restrict__ partials, float* __restrict__ out) {
  double s = 0.0;
#pragma unroll
  for (int i = 0; i < 8; ++i) s += partials[threadIdx.x + i * THREADS];
  for (int off = 32; off > 0; off >>= 1)
    s += __shfl_down(s, off, 64);
  __shared__ double smem[THREADS / 64];
  int lane = threadIdx.x & 63, wid = threadIdx.x >> 6;
  if (lane == 0) smem[wid] = s;
  __syncthreads();
  if (threadIdx.x == 0)
    out[0] = (float)((smem[0] + smem[1] + smem[2] + smem[3]) / (double)NPIX);
}

extern "C" void kernel_launch(void* const* d_in, const int* in_sizes, int n_in,
                              void* d_out, int out_size, void* d_ws, size_t ws_size,
                              hipStream_t stream) {
  const float* input = (const float*)d_in[0];
  const int* target = (const int*)d_in[1];
  float* out = (float*)d_out;

  // workspace: [0,16KiB) partials[2048]; pw (128 KiB) at +32KiB
  double* partials = (double*)d_ws;
  unsigned long long* pw = (unsigned long long*)((char*)d_ws + 32768);

  pack_bits<<<256, THREADS, 0, stream>>>(target, (unsigned short*)pw);
  fused_edt_row<<<RBLOCKS, THREADS, 0, stream>>>(pw, input, partials);
  reduce_partials<<<1, THREADS, 0, stream>>>(partials, out);
}